// Round 12
// baseline (74.319 us; speedup 1.0000x reference)
//
#include <hip/hip_runtime.h>
#include <math.h>

#define DIMS 3
#define NPTS 320
#define HID  128
#define RANK 64
#define CH   160   // c rows per block (half of NPTS)
#define LROW 128   // LDS bytes per c row (single bf16 table), XOR-swizzled

typedef __attribute__((ext_vector_type(8)))  short bf16x8;
typedef __attribute__((ext_vector_type(16))) float f32x16;

// round-to-nearest-even float -> bf16 bits
static __device__ __forceinline__ unsigned short f2bf_rn(float x) {
    union { float f; unsigned int u; } v; v.f = x;
    unsigned int r = v.u + 0x7fffu + ((v.u >> 16) & 1u);
    return (unsigned short)(r >> 16);
}
static __device__ __forceinline__ float bf2f(unsigned short h) {
    union { unsigned int u; float f; } v; v.u = ((unsigned int)h) << 16;
    return v.f;
}

// ---------------- Phase 1: per-dim MLP (R9 version - proven best) -----------
__global__ __launch_bounds__(HID)
void mlp_kernel(const float* __restrict__ xs,
                const float* __restrict__ W0, const float* __restrict__ b0,
                const float* __restrict__ W1, const float* __restrict__ b1,
                const float* __restrict__ W2, const float* __restrict__ b2,
                const float* __restrict__ W3, const float* __restrict__ b3,
                float* __restrict__ f01t,
                unsigned short* __restrict__ f2hi) {
    int blk = blockIdx.x;
    int d = blk / NPTS, n = blk % NPTS;
    int j = threadIdx.x;

    __shared__ float ha[HID];
    __shared__ float hb[HID];

    float x = xs[d * NPTS + n];

    ha[j] = tanhf(fmaf(x, W0[d * HID + j], b0[d * HID + j]));
    __syncthreads();

    {
        float acc = b1[d * HID + j];
        const float* w = W1 + d * HID * HID + j;
        #pragma unroll 16
        for (int k = 0; k < HID; ++k) acc = fmaf(ha[k], w[k * HID], acc);
        hb[j] = tanhf(acc);
    }
    __syncthreads();

    {
        float acc = b2[d * HID + j];
        const float* w = W2 + d * HID * HID + j;
        #pragma unroll 16
        for (int k = 0; k < HID; ++k) acc = fmaf(hb[k], w[k * HID], acc);
        ha[j] = tanhf(acc);
    }
    __syncthreads();

    if (j < RANK) {
        float acc = b3[d * RANK + j];
        const float* w = W3 + d * HID * RANK + j;
        #pragma unroll 16
        for (int k = 0; k < HID; ++k) acc = fmaf(ha[k], w[k * RANK], acc);

        if (d == 0) {
            f01t[n * RANK + j] = acc;                    // f0t[a][r]
        } else if (d == 1) {
            f01t[(NPTS + n) * RANK + j] = acc;           // f1t[b][r]
        } else {
            f2hi[n * RANK + j] = f2bf_rn(acc);           // single-rounded B
        }
    }
}

// ---------------- Phase 2: work-stealing CP via 32x32x16 bf16 MFMA ----------
// R9 inner loop byte-identical. Work distribution: 16 pools (XCD-class x
// c-half); pool = bid&7 owns contiguous 200-tile range, 64 blocks per
// (pool, c-half) pull tiles via atomicAdd -> no static 4-vs-3-round tail,
// per-XCD contiguous output region.
__global__ __launch_bounds__(128, 2)
void cp_mfma_kernel(const float* __restrict__ f01t,
                    const unsigned short* __restrict__ f2hi,
                    int* __restrict__ ctr,
                    float* __restrict__ out) {
    const int tx = threadIdx.x;
    const int w  = tx >> 6;        // wave -> b sub-tile
    const int l  = tx & 63;
    const int lc = l & 31;         // A row(b) / B col(c) / D col(c)
    const int hw = l >> 5;         // half-wave -> k sub-group

    const int bid   = (int)blockIdx.x;
    const int pool  = bid & 7;           // = XCD (round-robin dispatch)
    const int chalf = (bid >> 3) & 1;
    const int c0    = chalf * CH;

    __shared__ char sB[CH * LROW];   // 20 KB
    __shared__ int  s_t;

    // ---- stage c-half of f2 once (1280 float4, 10/thread), swizzled ----
    #pragma unroll
    for (int i = 0; i < 10; ++i) {
        int idx = tx + i * 128;               // 0..1279
        int row = idx >> 3;                   // local c row
        int g   = (idx & 7) << 4;             // 16B slot within 128B row
        *(float4*)(&sB[row * LROW + (g ^ ((row & 7) << 4))]) =
            ((const float4*)f2hi)[c0 * 8 + idx];
    }
    __syncthreads();

    for (;;) {
        if (tx == 0) s_t = atomicAdd(&ctr[pool + 8 * chalf], 1);
        __syncthreads();
        const int tt = s_t;
        __syncthreads();
        if (tt >= 200) break;
        const int t = pool * 200 + tt;

        const int a   = t / 5;
        const int b0w = (t - a * 5) * 64 + w * 32;
        const float* f0p = f01t + (size_t)a * RANK + hw * 8;
        const float* f1p = f01t + (size_t)(NPTS + b0w + lc) * RANK + hw * 8;

        // ---- A fragments: g[j] = f0[a][k]*f1[b][k], k = ks*16 + hw*8 + j ----
        bf16x8 ahi[4], alo[4];
        #pragma unroll
        for (int ks = 0; ks < 4; ++ks) {
            const int k0 = ks * 16;
            float4 f0a = *(const float4*)(f0p + k0);
            float4 f0b = *(const float4*)(f0p + k0 + 4);
            float4 f1a = *(const float4*)(f1p + k0);
            float4 f1b = *(const float4*)(f1p + k0 + 4);

            float g[8];
            g[0] = f1a.x * f0a.x; g[1] = f1a.y * f0a.y;
            g[2] = f1a.z * f0a.z; g[3] = f1a.w * f0a.w;
            g[4] = f1b.x * f0b.x; g[5] = f1b.y * f0b.y;
            g[6] = f1b.z * f0b.z; g[7] = f1b.w * f0b.w;

            #pragma unroll
            for (int j = 0; j < 8; ++j) {
                unsigned short hi = f2bf_rn(g[j]);
                ahi[ks][j] = (short)hi;
                alo[ks][j] = (short)f2bf_rn(g[j] - bf2f(hi));
            }
        }

        // ---- 5 c-tiles of 32: 4 LDS reads + 8 MFMAs + 16 stores each ----
        #pragma unroll
        for (int ct = 0; ct < 5; ++ct) {
            const char* rowp = &sB[(ct * 32 + lc) * LROW];
            const int swz = ((ct * 32 + lc) & 7) << 4;

            f32x16 acc;
            #pragma unroll
            for (int jj = 0; jj < 16; ++jj) acc[jj] = 0.0f;

            #pragma unroll
            for (int ks = 0; ks < 4; ++ks) {
                const int base = ks * 32 + (hw << 4);       // k slot bytes
                bf16x8 b = *(const bf16x8*)(rowp + (base ^ swz));
                acc = __builtin_amdgcn_mfma_f32_32x32x16_bf16(ahi[ks], b, acc, 0, 0, 0);
                acc = __builtin_amdgcn_mfma_f32_32x32x16_bf16(alo[ks], b, acc, 0, 0, 0);
            }

            // D: col(c)=lc, row(b) = (q&3) + 8*(q>>2) + 4*hw
            float* obase = out + ((size_t)a * NPTS + b0w) * NPTS + c0 + ct * 32 + lc;
            #pragma unroll
            for (int q = 0; q < 16; ++q) {
                int row = (q & 3) + 8 * (q >> 2) + 4 * hw;
                obase[(size_t)row * NPTS] = acc[q];
            }
        }
    }
}

extern "C" void kernel_launch(void* const* d_in, const int* in_sizes, int n_in,
                              void* d_out, int out_size, void* d_ws, size_t ws_size,
                              hipStream_t stream) {
    const float* xs = (const float*)d_in[0];
    const float* W0 = (const float*)d_in[1];
    const float* b0 = (const float*)d_in[2];
    const float* W1 = (const float*)d_in[3];
    const float* b1 = (const float*)d_in[4];
    const float* W2 = (const float*)d_in[5];
    const float* b2 = (const float*)d_in[6];
    const float* W3 = (const float*)d_in[7];
    const float* b3 = (const float*)d_in[8];

    // workspace: f01t float[2][NPTS][RANK] (163840 B) | f2hi ushort[NPTS][RANK]
    // (40960 B) | 16 int work-steal counters (64 B)
    float* f01t = (float*)d_ws;
    unsigned short* f2hi = (unsigned short*)((char*)d_ws + 2 * NPTS * RANK * 4);
    int* ctr = (int*)((char*)d_ws + 2 * NPTS * RANK * 4 + NPTS * RANK * 2);
    float* out = (float*)d_out;

    hipMemsetAsync(ctr, 0, 16 * sizeof(int), stream);

    mlp_kernel<<<dim3(DIMS * NPTS), dim3(HID), 0, stream>>>(
        xs, W0, b0, W1, b1, W2, b2, W3, b3, f01t, f2hi);

    cp_mfma_kernel<<<dim3(1024), dim3(128), 0, stream>>>(f01t, f2hi, ctr, out);
}

// Round 13
// 46.604 us; speedup vs baseline: 1.5947x; 1.5947x over previous
//
#include <hip/hip_runtime.h>
#include <math.h>

#define DIMS 3
#define NPTS 320
#define HID  128
#define RANK 64
#define CH   160   // c rows per block (half of NPTS)
#define LROW 128   // LDS bytes per c row (single bf16 table), XOR-swizzled
#define MPTS 8     // points per mlp block

typedef __attribute__((ext_vector_type(8)))  short bf16x8;
typedef __attribute__((ext_vector_type(16))) float f32x16;

// round-to-nearest-even float -> bf16 bits
static __device__ __forceinline__ unsigned short f2bf_rn(float x) {
    union { float f; unsigned int u; } v; v.f = x;
    unsigned int r = v.u + 0x7fffu + ((v.u >> 16) & 1u);
    return (unsigned short)(r >> 16);
}
static __device__ __forceinline__ float bf2f(unsigned short h) {
    union { unsigned int u; float f; } v; v.u = ((unsigned int)h) << 16;
    return v.f;
}

// ---------------- Phase 1: ILP-batched per-dim MLP --------------------------
// 120 blocks x 256 thr; thread = (hidden unit j, sub) owning 4 points.
// Each weight load feeds 4 independent FMA chains (4x ILP, 1/4 loads/point).
// Per-point arithmetic order identical to the R9 mlp (same fmaf chain, same
// tanhf) -> bitwise-identical factor tables.
__global__ __launch_bounds__(256)
void mlp_kernel(const float* __restrict__ xs,
                const float* __restrict__ W0, const float* __restrict__ b0,
                const float* __restrict__ W1, const float* __restrict__ b1,
                const float* __restrict__ W2, const float* __restrict__ b2,
                const float* __restrict__ W3, const float* __restrict__ b3,
                float* __restrict__ f01t,
                unsigned short* __restrict__ f2hi) {
    const int blk = blockIdx.x;
    const int d   = blk / (NPTS / MPTS);
    const int n0  = (blk - d * (NPTS / MPTS)) * MPTS;
    const int j   = threadIdx.x & (HID - 1);
    const int sub = threadIdx.x >> 7;          // 0/1

    __shared__ float ha[MPTS][HID];
    __shared__ float hb[MPTS][HID];

    // ---- layer 0 ----
    {
        float w = W0[d * HID + j], bb = b0[d * HID + j];
        #pragma unroll
        for (int pp = 0; pp < 4; ++pp) {
            int p = pp * 2 + sub;
            float x = xs[d * NPTS + n0 + p];
            ha[p][j] = tanhf(fmaf(x, w, bb));
        }
    }
    __syncthreads();

    // ---- layer 1 ----
    {
        float acc[4];
        #pragma unroll
        for (int pp = 0; pp < 4; ++pp) acc[pp] = b1[d * HID + j];
        const float* w = W1 + d * HID * HID + j;
        #pragma unroll 8
        for (int k = 0; k < HID; ++k) {
            float wv = w[k * HID];
            #pragma unroll
            for (int pp = 0; pp < 4; ++pp)
                acc[pp] = fmaf(ha[pp * 2 + sub][k], wv, acc[pp]);
        }
        #pragma unroll
        for (int pp = 0; pp < 4; ++pp) hb[pp * 2 + sub][j] = tanhf(acc[pp]);
    }
    __syncthreads();

    // ---- layer 2 ----
    {
        float acc[4];
        #pragma unroll
        for (int pp = 0; pp < 4; ++pp) acc[pp] = b2[d * HID + j];
        const float* w = W2 + d * HID * HID + j;
        #pragma unroll 8
        for (int k = 0; k < HID; ++k) {
            float wv = w[k * HID];
            #pragma unroll
            for (int pp = 0; pp < 4; ++pp)
                acc[pp] = fmaf(hb[pp * 2 + sub][k], wv, acc[pp]);
        }
        __syncthreads();   // all hb reads done before ha overwrite? reads above precede this barrier; safe to write ha after
        #pragma unroll
        for (int pp = 0; pp < 4; ++pp) ha[pp * 2 + sub][j] = tanhf(acc[pp]);
    }
    __syncthreads();

    // ---- layer 3 (RANK outputs; threads j<RANK of both subs, 4 pts each) ----
    if (j < RANK) {
        float acc[4];
        #pragma unroll
        for (int pp = 0; pp < 4; ++pp) acc[pp] = b3[d * RANK + j];
        const float* w = W3 + d * HID * RANK + j;
        #pragma unroll 8
        for (int k = 0; k < HID; ++k) {
            float wv = w[k * RANK];
            #pragma unroll
            for (int pp = 0; pp < 4; ++pp)
                acc[pp] = fmaf(ha[pp * 2 + sub][k], wv, acc[pp]);
        }
        #pragma unroll
        for (int pp = 0; pp < 4; ++pp) {
            int n = n0 + pp * 2 + sub;
            if (d == 0) {
                f01t[n * RANK + j] = acc[pp];                // f0t[a][r]
            } else if (d == 1) {
                f01t[(NPTS + n) * RANK + j] = acc[pp];       // f1t[b][r]
            } else {
                f2hi[n * RANK + j] = f2bf_rn(acc[pp]);       // single-rounded B
            }
        }
    }
}

// ---------------- Phase 2: persistent-block CP via 32x32x16 bf16 MFMA -------
// BYTE-IDENTICAL to R9 (proven best): 1024 blocks x 128 thr (2 waves), block
// owns a c-half staged once (20 KB, swizzled); per ct: 4 ds_read_b128 +
// 8 MFMAs + 16 interleaved full-line stores. A built in-register hi/lo.
__global__ __launch_bounds__(128, 2)
void cp_mfma_kernel(const float* __restrict__ f01t,
                    const unsigned short* __restrict__ f2hi,
                    float* __restrict__ out) {
    const int tx = threadIdx.x;
    const int w  = tx >> 6;        // wave -> b sub-tile
    const int l  = tx & 63;
    const int lc = l & 31;         // A row(b) / B col(c) / D col(c)
    const int hw = l >> 5;         // half-wave -> k sub-group

    const int c0 = (blockIdx.x & 1) * CH;

    __shared__ char sB[CH * LROW];   // 20 KB

    // ---- stage c-half of f2 once (1280 float4, 10/thread), swizzled ----
    #pragma unroll
    for (int i = 0; i < 10; ++i) {
        int idx = tx + i * 128;               // 0..1279
        int row = idx >> 3;                   // local c row
        int g   = (idx & 7) << 4;             // 16B slot within 128B row
        *(float4*)(&sB[row * LROW + (g ^ ((row & 7) << 4))]) =
            ((const float4*)f2hi)[c0 * 8 + idx];
    }
    __syncthreads();

    for (int t = blockIdx.x >> 1; t < NPTS * 5; t += 512) {
        const int a   = t / 5;
        const int b0w = (t - a * 5) * 64 + w * 32;
        const float* f0p = f01t + (size_t)a * RANK + hw * 8;
        const float* f1p = f01t + (size_t)(NPTS + b0w + lc) * RANK + hw * 8;

        // ---- A fragments: g[j] = f0[a][k]*f1[b][k], k = ks*16 + hw*8 + j ----
        bf16x8 ahi[4], alo[4];
        #pragma unroll
        for (int ks = 0; ks < 4; ++ks) {
            const int k0 = ks * 16;
            float4 f0a = *(const float4*)(f0p + k0);
            float4 f0b = *(const float4*)(f0p + k0 + 4);
            float4 f1a = *(const float4*)(f1p + k0);
            float4 f1b = *(const float4*)(f1p + k0 + 4);

            float g[8];
            g[0] = f1a.x * f0a.x; g[1] = f1a.y * f0a.y;
            g[2] = f1a.z * f0a.z; g[3] = f1a.w * f0a.w;
            g[4] = f1b.x * f0b.x; g[5] = f1b.y * f0b.y;
            g[6] = f1b.z * f0b.z; g[7] = f1b.w * f0b.w;

            #pragma unroll
            for (int j = 0; j < 8; ++j) {
                unsigned short hi = f2bf_rn(g[j]);
                ahi[ks][j] = (short)hi;
                alo[ks][j] = (short)f2bf_rn(g[j] - bf2f(hi));
            }
        }

        // ---- 5 c-tiles of 32: 4 LDS reads + 8 MFMAs + 16 stores each ----
        #pragma unroll
        for (int ct = 0; ct < 5; ++ct) {
            const char* rowp = &sB[(ct * 32 + lc) * LROW];
            const int swz = ((ct * 32 + lc) & 7) << 4;

            f32x16 acc;
            #pragma unroll
            for (int jj = 0; jj < 16; ++jj) acc[jj] = 0.0f;

            #pragma unroll
            for (int ks = 0; ks < 4; ++ks) {
                const int base = ks * 32 + (hw << 4);       // k slot bytes
                bf16x8 b = *(const bf16x8*)(rowp + (base ^ swz));
                acc = __builtin_amdgcn_mfma_f32_32x32x16_bf16(ahi[ks], b, acc, 0, 0, 0);
                acc = __builtin_amdgcn_mfma_f32_32x32x16_bf16(alo[ks], b, acc, 0, 0, 0);
            }

            // D: col(c)=lc, row(b) = (q&3) + 8*(q>>2) + 4*hw
            float* obase = out + ((size_t)a * NPTS + b0w) * NPTS + c0 + ct * 32 + lc;
            #pragma unroll
            for (int q = 0; q < 16; ++q) {
                int row = (q & 3) + 8 * (q >> 2) + 4 * hw;
                obase[(size_t)row * NPTS] = acc[q];
            }
        }
    }
}

extern "C" void kernel_launch(void* const* d_in, const int* in_sizes, int n_in,
                              void* d_out, int out_size, void* d_ws, size_t ws_size,
                              hipStream_t stream) {
    const float* xs = (const float*)d_in[0];
    const float* W0 = (const float*)d_in[1];
    const float* b0 = (const float*)d_in[2];
    const float* W1 = (const float*)d_in[3];
    const float* b1 = (const float*)d_in[4];
    const float* W2 = (const float*)d_in[5];
    const float* b2 = (const float*)d_in[6];
    const float* W3 = (const float*)d_in[7];
    const float* b3 = (const float*)d_in[8];

    // workspace: f01t float[2][NPTS][RANK] | f2hi ushort[NPTS][RANK]
    float* f01t = (float*)d_ws;
    unsigned short* f2hi = (unsigned short*)((char*)d_ws + 2 * NPTS * RANK * 4);
    float* out = (float*)d_out;

    mlp_kernel<<<dim3(DIMS * NPTS / MPTS), dim3(256), 0, stream>>>(
        xs, W0, b0, W1, b1, W2, b2, W3, b3, f01t, f2hi);

    cp_mfma_kernel<<<dim3(1024), dim3(128), 0, stream>>>(f01t, f2hi, out);
}

// Round 14
// 37.867 us; speedup vs baseline: 1.9626x; 1.2307x over previous
//
#include <hip/hip_runtime.h>
#include <math.h>

#define DIMS 3
#define NPTS 320
#define HID  128
#define RANK 64
#define CH   160   // c rows per block (half of NPTS)
#define LROW 128   // LDS bytes per c row (single bf16 table), XOR-swizzled

typedef __attribute__((ext_vector_type(8)))  short bf16x8;
typedef __attribute__((ext_vector_type(16))) float f32x16;

// round-to-nearest-even float -> bf16 bits
static __device__ __forceinline__ unsigned short f2bf_rn(float x) {
    union { float f; unsigned int u; } v; v.f = x;
    unsigned int r = v.u + 0x7fffu + ((v.u >> 16) & 1u);
    return (unsigned short)(r >> 16);
}
static __device__ __forceinline__ float bf2f(unsigned short h) {
    union { unsigned int u; float f; } v; v.u = ((unsigned int)h) << 16;
    return v.f;
}

// ---------------- Phase 1: per-dim MLP, 4-way k-split -----------------------
// 960 blocks (one per point, same as proven-best R9) but 512 threads:
// thread = (hidden unit j = tx&127, k-quarter kq = tx>>7). Partial dot over
// 32 k's (4x shorter chain), LDS reduce, single-lane tanh. 4x the waves of
// R9's mlp -> load latency hidden by TLP (R10/R13 showed TLP, not ILP, is
// what this kernel needs).
__global__ __launch_bounds__(512)
void mlp_kernel(const float* __restrict__ xs,
                const float* __restrict__ W0, const float* __restrict__ b0,
                const float* __restrict__ W1, const float* __restrict__ b1,
                const float* __restrict__ W2, const float* __restrict__ b2,
                const float* __restrict__ W3, const float* __restrict__ b3,
                float* __restrict__ f01t,
                unsigned short* __restrict__ f2hi) {
    const int blk = blockIdx.x;
    const int d = blk / NPTS, n = blk % NPTS;
    const int j  = threadIdx.x & (HID - 1);
    const int kq = threadIdx.x >> 7;          // 0..3
    const int k0 = kq * 32;

    __shared__ float ha[HID];
    __shared__ float hb[HID];
    __shared__ float part[4][HID];

    const float x = xs[d * NPTS + n];

    // ---- layer 0 ----
    if (kq == 0) {
        ha[j] = tanhf(fmaf(x, W0[d * HID + j], b0[d * HID + j]));
    }
    __syncthreads();

    // ---- layer 1: partial over k in [k0, k0+32) ----
    {
        float acc = 0.0f;
        const float* w = W1 + d * HID * HID + j;
        #pragma unroll 16
        for (int k = 0; k < 32; ++k) acc = fmaf(ha[k0 + k], w[(k0 + k) * HID], acc);
        part[kq][j] = acc;
    }
    __syncthreads();
    if (kq == 0) {
        float s = ((part[0][j] + part[1][j]) + (part[2][j] + part[3][j]))
                  + b1[d * HID + j];
        hb[j] = tanhf(s);
    }
    __syncthreads();

    // ---- layer 2 ----
    {
        float acc = 0.0f;
        const float* w = W2 + d * HID * HID + j;
        #pragma unroll 16
        for (int k = 0; k < 32; ++k) acc = fmaf(hb[k0 + k], w[(k0 + k) * HID], acc);
        part[kq][j] = acc;
    }
    __syncthreads();
    if (kq == 0) {
        float s = ((part[0][j] + part[1][j]) + (part[2][j] + part[3][j]))
                  + b2[d * HID + j];
        ha[j] = tanhf(s);
    }
    __syncthreads();

    // ---- layer 3: RANK outputs ----
    if (j < RANK) {
        float acc = 0.0f;
        const float* w = W3 + d * HID * RANK + j;
        #pragma unroll 16
        for (int k = 0; k < 32; ++k) acc = fmaf(ha[k0 + k], w[(k0 + k) * RANK], acc);
        part[kq][j] = acc;
    }
    __syncthreads();
    if (kq == 0 && j < RANK) {
        float s = ((part[0][j] + part[1][j]) + (part[2][j] + part[3][j]))
                  + b3[d * RANK + j];
        if (d == 0) {
            f01t[n * RANK + j] = s;                      // f0t[a][r]
        } else if (d == 1) {
            f01t[(NPTS + n) * RANK + j] = s;             // f1t[b][r]
        } else {
            f2hi[n * RANK + j] = f2bf_rn(s);             // single-rounded B
        }
    }
}

// ---------------- Phase 2: persistent-block CP via 32x32x16 bf16 MFMA -------
// BYTE-IDENTICAL to R9 (twice-confirmed best): 1024 blocks x 128 thr (2
// waves), block owns a c-half staged once (20 KB, swizzled); per ct: 4
// ds_read_b128 + 8 MFMAs + 16 interleaved full-line stores. A in-register
// hi/lo split.
__global__ __launch_bounds__(128, 2)
void cp_mfma_kernel(const float* __restrict__ f01t,
                    const unsigned short* __restrict__ f2hi,
                    float* __restrict__ out) {
    const int tx = threadIdx.x;
    const int w  = tx >> 6;        // wave -> b sub-tile
    const int l  = tx & 63;
    const int lc = l & 31;         // A row(b) / B col(c) / D col(c)
    const int hw = l >> 5;         // half-wave -> k sub-group

    const int c0 = (blockIdx.x & 1) * CH;

    __shared__ char sB[CH * LROW];   // 20 KB

    // ---- stage c-half of f2 once (1280 float4, 10/thread), swizzled ----
    #pragma unroll
    for (int i = 0; i < 10; ++i) {
        int idx = tx + i * 128;               // 0..1279
        int row = idx >> 3;                   // local c row
        int g   = (idx & 7) << 4;             // 16B slot within 128B row
        *(float4*)(&sB[row * LROW + (g ^ ((row & 7) << 4))]) =
            ((const float4*)f2hi)[c0 * 8 + idx];
    }
    __syncthreads();

    for (int t = blockIdx.x >> 1; t < NPTS * 5; t += 512) {
        const int a   = t / 5;
        const int b0w = (t - a * 5) * 64 + w * 32;
        const float* f0p = f01t + (size_t)a * RANK + hw * 8;
        const float* f1p = f01t + (size_t)(NPTS + b0w + lc) * RANK + hw * 8;

        // ---- A fragments: g[j] = f0[a][k]*f1[b][k], k = ks*16 + hw*8 + j ----
        bf16x8 ahi[4], alo[4];
        #pragma unroll
        for (int ks = 0; ks < 4; ++ks) {
            const int k0 = ks * 16;
            float4 f0a = *(const float4*)(f0p + k0);
            float4 f0b = *(const float4*)(f0p + k0 + 4);
            float4 f1a = *(const float4*)(f1p + k0);
            float4 f1b = *(const float4*)(f1p + k0 + 4);

            float g[8];
            g[0] = f1a.x * f0a.x; g[1] = f1a.y * f0a.y;
            g[2] = f1a.z * f0a.z; g[3] = f1a.w * f0a.w;
            g[4] = f1b.x * f0b.x; g[5] = f1b.y * f0b.y;
            g[6] = f1b.z * f0b.z; g[7] = f1b.w * f0b.w;

            #pragma unroll
            for (int j = 0; j < 8; ++j) {
                unsigned short hi = f2bf_rn(g[j]);
                ahi[ks][j] = (short)hi;
                alo[ks][j] = (short)f2bf_rn(g[j] - bf2f(hi));
            }
        }

        // ---- 5 c-tiles of 32: 4 LDS reads + 8 MFMAs + 16 stores each ----
        #pragma unroll
        for (int ct = 0; ct < 5; ++ct) {
            const char* rowp = &sB[(ct * 32 + lc) * LROW];
            const int swz = ((ct * 32 + lc) & 7) << 4;

            f32x16 acc;
            #pragma unroll
            for (int jj = 0; jj < 16; ++jj) acc[jj] = 0.0f;

            #pragma unroll
            for (int ks = 0; ks < 4; ++ks) {
                const int base = ks * 32 + (hw << 4);       // k slot bytes
                bf16x8 b = *(const bf16x8*)(rowp + (base ^ swz));
                acc = __builtin_amdgcn_mfma_f32_32x32x16_bf16(ahi[ks], b, acc, 0, 0, 0);
                acc = __builtin_amdgcn_mfma_f32_32x32x16_bf16(alo[ks], b, acc, 0, 0, 0);
            }

            // D: col(c)=lc, row(b) = (q&3) + 8*(q>>2) + 4*hw
            float* obase = out + ((size_t)a * NPTS + b0w) * NPTS + c0 + ct * 32 + lc;
            #pragma unroll
            for (int q = 0; q < 16; ++q) {
                int row = (q & 3) + 8 * (q >> 2) + 4 * hw;
                obase[(size_t)row * NPTS] = acc[q];
            }
        }
    }
}

extern "C" void kernel_launch(void* const* d_in, const int* in_sizes, int n_in,
                              void* d_out, int out_size, void* d_ws, size_t ws_size,
                              hipStream_t stream) {
    const float* xs = (const float*)d_in[0];
    const float* W0 = (const float*)d_in[1];
    const float* b0 = (const float*)d_in[2];
    const float* W1 = (const float*)d_in[3];
    const float* b1 = (const float*)d_in[4];
    const float* W2 = (const float*)d_in[5];
    const float* b2 = (const float*)d_in[6];
    const float* W3 = (const float*)d_in[7];
    const float* b3 = (const float*)d_in[8];

    // workspace: f01t float[2][NPTS][RANK] | f2hi ushort[NPTS][RANK]
    float* f01t = (float*)d_ws;
    unsigned short* f2hi = (unsigned short*)((char*)d_ws + 2 * NPTS * RANK * 4);
    float* out = (float*)d_out;

    mlp_kernel<<<dim3(DIMS * NPTS), dim3(512), 0, stream>>>(
        xs, W0, b0, W1, b1, W2, b2, W3, b3, f01t, f2hi);

    cp_mfma_kernel<<<dim3(1024), dim3(128), 0, stream>>>(f01t, f2hi, out);
}